// Round 2
// baseline (239.124 us; speedup 1.0000x reference)
//
#include <hip/hip_runtime.h>

// Problem constants (fixed by setup_inputs)
constexpr int B  = 16;
constexpr int C  = 3;
constexpr int H  = 256;
constexpr int W  = 256;
constexpr int NC = 35;
constexpr int HW   = H * W;         // 65536
constexpr long NPIX = (long)B * HW; // 1,048,576
constexpr int VEC  = 4;             // pixels per thread
constexpr int BLOCK = 256;
constexpr int GRID  = (int)(NPIX / VEC / BLOCK); // 1024

__global__ __launch_bounds__(BLOCK) void labelmix_mse_kernel(
    const float* __restrict__ real,   // [B,C,H,W]
    const float* __restrict__ gen,    // [B,C,H,W]
    const float* __restrict__ seg,    // [B,NC,H,W]
    const float* __restrict__ rdisc,  // [B,1,H,W]
    const float* __restrict__ gdisc,  // [B,1,H,W]
    const float* __restrict__ w,      // [1, C+NC]
    const int*   __restrict__ lut,    // [NC] in {0,1}
    float* __restrict__ out)          // [1]
{
    const int tid  = blockIdx.x * blockDim.x + threadIdx.x;
    const long pix = (long)tid * VEC;          // first of 4 consecutive pixels
    const int b    = (int)(pix / HW);          // same b for all 4 (HW % 4 == 0)
    const int hw   = (int)(pix % HW);

    // Uniform scalar prefetch of weights + LUT (constant indices => s_loads).
    float wc_all[C + NC];
    #pragma unroll
    for (int c = 0; c < C + NC; ++c) wc_all[c] = w[c];

    unsigned long long mask = 0ull;
    #pragma unroll
    for (int c = 0; c < NC; ++c)
        mask |= ((unsigned long long)(lut[c] & 1)) << c;

    // ---- single pass over seg channels: argmax + seg-part of the 1x1 conv ----
    const float4* seg4 = (const float4*)(seg + (long)b * NC * HW + hw);
    const int cstride = HW / VEC; // float4 stride between channels

    float4 v0 = seg4[0];
    float bestv[VEC] = {v0.x, v0.y, v0.z, v0.w};
    int   bidx[VEC]  = {0, 0, 0, 0};
    float segdot[VEC];
    {
        const float w0 = wc_all[C + 0];
        segdot[0] = v0.x * w0; segdot[1] = v0.y * w0;
        segdot[2] = v0.z * w0; segdot[3] = v0.w * w0;
    }
    #pragma unroll
    for (int c = 1; c < NC; ++c) {
        float4 v = seg4[(size_t)c * cstride];
        const float wc = wc_all[C + c];
        float vv[VEC] = {v.x, v.y, v.z, v.w};
        #pragma unroll
        for (int k = 0; k < VEC; ++k) {
            segdot[k] = fmaf(vv[k], wc, segdot[k]);
            if (vv[k] > bestv[k]) { bestv[k] = vv[k]; bidx[k] = c; }
        }
    }

    // tm per pixel in {0,1}
    float tm[VEC];
    #pragma unroll
    for (int k = 0; k < VEC; ++k)
        tm[k] = (float)((mask >> bidx[k]) & 1ull);

    // ---- image part of the conv: (tm*real + (1-tm)*gen) . w[0:3] ----
    const float4* r4 = (const float4*)(real + (long)b * C * HW + hw);
    const float4* g4 = (const float4*)(gen  + (long)b * C * HW + hw);
    float imgdot[VEC] = {0.f, 0.f, 0.f, 0.f};
    #pragma unroll
    for (int c = 0; c < C; ++c) {
        float4 rv = r4[(size_t)c * cstride];
        float4 gv = g4[(size_t)c * cstride];
        const float wc = wc_all[c];
        float rr[VEC] = {rv.x, rv.y, rv.z, rv.w};
        float gg[VEC] = {gv.x, gv.y, gv.z, gv.w};
        #pragma unroll
        for (int k = 0; k < VEC; ++k) {
            const float mix = tm[k] * rr[k] + (1.f - tm[k]) * gg[k];
            imgdot[k] = fmaf(mix, wc, imgdot[k]);
        }
    }

    // ---- mixed disc target + squared error ----
    float4 rd = *(const float4*)(rdisc + (long)b * HW + hw);
    float4 gd = *(const float4*)(gdisc + (long)b * HW + hw);
    float rr[VEC] = {rd.x, rd.y, rd.z, rd.w};
    float gg[VEC] = {gd.x, gd.y, gd.z, gd.w};

    float sum = 0.f;
    #pragma unroll
    for (int k = 0; k < VEC; ++k) {
        const float target = tm[k] * rr[k] + (1.f - tm[k]) * gg[k];
        const float d = segdot[k] + imgdot[k] - target;
        sum = fmaf(d, d, sum);
    }
    sum *= (1.0f / (float)NPIX);

    // ---- wave (64) reduce, then block reduce, then one atomic per block ----
    #pragma unroll
    for (int off = 32; off > 0; off >>= 1)
        sum += __shfl_down(sum, off, 64);

    __shared__ float lsum[BLOCK / 64];
    const int wid  = threadIdx.x >> 6;
    const int lane = threadIdx.x & 63;
    if (lane == 0) lsum[wid] = sum;
    __syncthreads();
    if (threadIdx.x == 0) {
        float s = 0.f;
        #pragma unroll
        for (int i = 0; i < BLOCK / 64; ++i) s += lsum[i];
        atomicAdd(out, s);
    }
}

extern "C" void kernel_launch(void* const* d_in, const int* in_sizes, int n_in,
                              void* d_out, int out_size, void* d_ws, size_t ws_size,
                              hipStream_t stream) {
    const float* real  = (const float*)d_in[0];
    const float* gen   = (const float*)d_in[1];
    const float* seg   = (const float*)d_in[2];
    const float* rdisc = (const float*)d_in[3];
    const float* gdisc = (const float*)d_in[4];
    const float* w     = (const float*)d_in[5];
    const int*   lut   = (const int*)d_in[6];
    float* out = (float*)d_out;

    // d_out is poisoned (0xAA) before every call — zero it for the atomic sum.
    hipMemsetAsync(out, 0, sizeof(float), stream);

    labelmix_mse_kernel<<<GRID, BLOCK, 0, stream>>>(
        real, gen, seg, rdisc, gdisc, w, lut, out);
}

// Round 3
// 221.002 us; speedup vs baseline: 1.0820x; 1.0820x over previous
//
#include <hip/hip_runtime.h>

// Problem constants (fixed by setup_inputs)
constexpr int B  = 16;
constexpr int C  = 3;
constexpr int H  = 256;
constexpr int W  = 256;
constexpr int NC = 35;
constexpr int HW   = H * W;         // 65536
constexpr long NPIX = (long)B * HW; // 1,048,576
constexpr int VEC  = 4;             // pixels per thread
constexpr int BLOCK = 256;
constexpr int GRID  = (int)(NPIX / VEC / BLOCK); // 1024

typedef float v4f __attribute__((ext_vector_type(4)));

__global__ __launch_bounds__(BLOCK, 4) void labelmix_partial_kernel(
    const float* __restrict__ real,   // [B,C,H,W]
    const float* __restrict__ gen,    // [B,C,H,W]
    const float* __restrict__ seg,    // [B,NC,H,W]
    const float* __restrict__ rdisc,  // [B,1,H,W]
    const float* __restrict__ gdisc,  // [B,1,H,W]
    const float* __restrict__ w,      // [1, C+NC]
    const int*   __restrict__ lut,    // [NC] in {0,1}
    float* __restrict__ partial)      // [GRID]
{
    const int tid  = blockIdx.x * blockDim.x + threadIdx.x;
    const long pix = (long)tid * VEC;          // first of 4 consecutive pixels
    const int b    = (int)(pix / HW);          // same b for all 4 (HW % 4 == 0)
    const int hw   = (int)(pix % HW);

    // Uniform scalar prefetch of weights + LUT (constant indices => s_loads).
    float wc_all[C + NC];
    #pragma unroll
    for (int c = 0; c < C + NC; ++c) wc_all[c] = w[c];

    unsigned long long mask = 0ull;
    #pragma unroll
    for (int c = 0; c < NC; ++c)
        mask |= ((unsigned long long)(lut[c] & 1)) << c;

    // ---- single pass over seg channels: argmax + seg-part of the 1x1 conv ----
    const v4f* seg4 = (const v4f*)(seg + (long)b * NC * HW + hw);
    const int cstride = HW / VEC; // v4f stride between channels

    v4f v0 = __builtin_nontemporal_load(&seg4[0]);
    float bestv[VEC] = {v0.x, v0.y, v0.z, v0.w};
    int   bidx[VEC]  = {0, 0, 0, 0};
    float segdot[VEC];
    {
        const float w0 = wc_all[C + 0];
        segdot[0] = v0.x * w0; segdot[1] = v0.y * w0;
        segdot[2] = v0.z * w0; segdot[3] = v0.w * w0;
    }
    #pragma unroll
    for (int c = 1; c < NC; ++c) {
        v4f v = __builtin_nontemporal_load(&seg4[(size_t)c * cstride]);
        const float wc = wc_all[C + c];
        float vv[VEC] = {v.x, v.y, v.z, v.w};
        #pragma unroll
        for (int k = 0; k < VEC; ++k) {
            segdot[k] = fmaf(vv[k], wc, segdot[k]);
            if (vv[k] > bestv[k]) { bestv[k] = vv[k]; bidx[k] = c; }
        }
    }

    // tm per pixel in {0,1}
    float tm[VEC];
    #pragma unroll
    for (int k = 0; k < VEC; ++k)
        tm[k] = (float)((mask >> bidx[k]) & 1ull);

    // ---- image part of the conv: (tm*real + (1-tm)*gen) . w[0:3] ----
    const v4f* r4 = (const v4f*)(real + (long)b * C * HW + hw);
    const v4f* g4 = (const v4f*)(gen  + (long)b * C * HW + hw);
    float imgdot[VEC] = {0.f, 0.f, 0.f, 0.f};
    #pragma unroll
    for (int c = 0; c < C; ++c) {
        v4f rv = __builtin_nontemporal_load(&r4[(size_t)c * cstride]);
        v4f gv = __builtin_nontemporal_load(&g4[(size_t)c * cstride]);
        const float wc = wc_all[c];
        float rr[VEC] = {rv.x, rv.y, rv.z, rv.w};
        float gg[VEC] = {gv.x, gv.y, gv.z, gv.w};
        #pragma unroll
        for (int k = 0; k < VEC; ++k) {
            const float mix = tm[k] * rr[k] + (1.f - tm[k]) * gg[k];
            imgdot[k] = fmaf(mix, wc, imgdot[k]);
        }
    }

    // ---- mixed disc target + squared error ----
    v4f rd = __builtin_nontemporal_load((const v4f*)(rdisc + (long)b * HW + hw));
    v4f gd = __builtin_nontemporal_load((const v4f*)(gdisc + (long)b * HW + hw));
    float rr[VEC] = {rd.x, rd.y, rd.z, rd.w};
    float gg[VEC] = {gd.x, gd.y, gd.z, gd.w};

    float sum = 0.f;
    #pragma unroll
    for (int k = 0; k < VEC; ++k) {
        const float target = tm[k] * rr[k] + (1.f - tm[k]) * gg[k];
        const float d = segdot[k] + imgdot[k] - target;
        sum = fmaf(d, d, sum);
    }

    // ---- wave (64) reduce, then block reduce, one partial per block ----
    #pragma unroll
    for (int off = 32; off > 0; off >>= 1)
        sum += __shfl_down(sum, off, 64);

    __shared__ float lsum[BLOCK / 64];
    const int wid  = threadIdx.x >> 6;
    const int lane = threadIdx.x & 63;
    if (lane == 0) lsum[wid] = sum;
    __syncthreads();
    if (threadIdx.x == 0) {
        float s = 0.f;
        #pragma unroll
        for (int i = 0; i < BLOCK / 64; ++i) s += lsum[i];
        partial[blockIdx.x] = s;   // no atomic, no init needed
    }
}

// Deterministic finalize: 1024 partials -> scalar mean.
__global__ __launch_bounds__(256) void finalize_kernel(
    const float* __restrict__ partial, float* __restrict__ out)
{
    const v4f* p4 = (const v4f*)partial;           // 1024 / 4 = 256
    v4f v = p4[threadIdx.x];
    float sum = v.x + v.y + v.z + v.w;

    #pragma unroll
    for (int off = 32; off > 0; off >>= 1)
        sum += __shfl_down(sum, off, 64);

    __shared__ float lsum[4];
    const int wid  = threadIdx.x >> 6;
    const int lane = threadIdx.x & 63;
    if (lane == 0) lsum[wid] = sum;
    __syncthreads();
    if (threadIdx.x == 0) {
        float s = lsum[0] + lsum[1] + lsum[2] + lsum[3];
        out[0] = s * (1.0f / (float)NPIX);
    }
}

extern "C" void kernel_launch(void* const* d_in, const int* in_sizes, int n_in,
                              void* d_out, int out_size, void* d_ws, size_t ws_size,
                              hipStream_t stream) {
    const float* real  = (const float*)d_in[0];
    const float* gen   = (const float*)d_in[1];
    const float* seg   = (const float*)d_in[2];
    const float* rdisc = (const float*)d_in[3];
    const float* gdisc = (const float*)d_in[4];
    const float* w     = (const float*)d_in[5];
    const int*   lut   = (const int*)d_in[6];
    float* out     = (float*)d_out;
    float* partial = (float*)d_ws;   // GRID floats of scratch

    labelmix_partial_kernel<<<GRID, BLOCK, 0, stream>>>(
        real, gen, seg, rdisc, gdisc, w, lut, partial);
    finalize_kernel<<<1, 256, 0, stream>>>(partial, out);
}

// Round 4
// 220.533 us; speedup vs baseline: 1.0843x; 1.0021x over previous
//
#include <hip/hip_runtime.h>

// Problem constants (fixed by setup_inputs)
constexpr int B  = 16;
constexpr int C  = 3;
constexpr int H  = 256;
constexpr int W  = 256;
constexpr int NC = 35;
constexpr int HW   = H * W;         // 65536
constexpr long NPIX = (long)B * HW; // 1,048,576
constexpr int VEC  = 4;             // pixels per thread
constexpr int BLOCK = 256;
constexpr int GRID  = (int)(NPIX / VEC / BLOCK); // 1024

typedef float v4f __attribute__((ext_vector_type(4)));

__global__ __launch_bounds__(BLOCK, 4) void labelmix_partial_kernel(
    const float* __restrict__ real,   // [B,C,H,W]
    const float* __restrict__ gen,    // [B,C,H,W]
    const float* __restrict__ seg,    // [B,NC,H,W]
    const float* __restrict__ rdisc,  // [B,1,H,W]
    const float* __restrict__ gdisc,  // [B,1,H,W]
    const float* __restrict__ w,      // [1, C+NC]
    const int*   __restrict__ lut,    // [NC] in {0,1}
    float* __restrict__ partial)      // [GRID]
{
    const int tid  = blockIdx.x * blockDim.x + threadIdx.x;
    const long pix = (long)tid * VEC;          // first of 4 consecutive pixels
    const int b    = (int)(pix / HW);          // same b for all 4 (HW % 4 == 0)
    const int hw   = (int)(pix % HW);

    // Uniform scalar prefetch of weights + LUT (constant indices => s_loads).
    float wc_all[C + NC];
    #pragma unroll
    for (int c = 0; c < C + NC; ++c) wc_all[c] = w[c];

    unsigned long long mask = 0ull;
    #pragma unroll
    for (int c = 0; c < NC; ++c)
        mask |= ((unsigned long long)(lut[c] & 1)) << c;

    const int cstride = HW / VEC; // v4f stride between channels

    // ---- issue ALL image/disc loads up front: independent of the seg chain,
    // they hide their full HBM latency behind the 35-channel seg loop.
    const v4f* r4 = (const v4f*)(real + (long)b * C * HW + hw);
    const v4f* g4 = (const v4f*)(gen  + (long)b * C * HW + hw);
    v4f rv[C], gv[C];
    #pragma unroll
    for (int c = 0; c < C; ++c) {
        rv[c] = __builtin_nontemporal_load(&r4[(size_t)c * cstride]);
        gv[c] = __builtin_nontemporal_load(&g4[(size_t)c * cstride]);
    }
    v4f rd = __builtin_nontemporal_load((const v4f*)(rdisc + (long)b * HW + hw));
    v4f gd = __builtin_nontemporal_load((const v4f*)(gdisc + (long)b * HW + hw));

    // ---- single pass over seg channels: argmax + seg-part of the 1x1 conv ----
    const v4f* seg4 = (const v4f*)(seg + (long)b * NC * HW + hw);

    v4f v0 = __builtin_nontemporal_load(&seg4[0]);
    float bestv[VEC] = {v0.x, v0.y, v0.z, v0.w};
    int   bidx[VEC]  = {0, 0, 0, 0};
    float segdot[VEC];
    {
        const float w0 = wc_all[C + 0];
        segdot[0] = v0.x * w0; segdot[1] = v0.y * w0;
        segdot[2] = v0.z * w0; segdot[3] = v0.w * w0;
    }
    #pragma unroll
    for (int c = 1; c < NC; ++c) {
        v4f v = __builtin_nontemporal_load(&seg4[(size_t)c * cstride]);
        const float wc = wc_all[C + c];
        float vv[VEC] = {v.x, v.y, v.z, v.w};
        #pragma unroll
        for (int k = 0; k < VEC; ++k) {
            segdot[k] = fmaf(vv[k], wc, segdot[k]);
            if (vv[k] > bestv[k]) { bestv[k] = vv[k]; bidx[k] = c; }
        }
    }

    // tm per pixel in {0,1}
    float tm[VEC];
    #pragma unroll
    for (int k = 0; k < VEC; ++k)
        tm[k] = (float)((mask >> bidx[k]) & 1ull);

    // ---- image part of the conv: (tm*real + (1-tm)*gen) . w[0:3] ----
    float imgdot[VEC] = {0.f, 0.f, 0.f, 0.f};
    #pragma unroll
    for (int c = 0; c < C; ++c) {
        const float wc = wc_all[c];
        float rr[VEC] = {rv[c].x, rv[c].y, rv[c].z, rv[c].w};
        float gg[VEC] = {gv[c].x, gv[c].y, gv[c].z, gv[c].w};
        #pragma unroll
        for (int k = 0; k < VEC; ++k) {
            const float mix = tm[k] * rr[k] + (1.f - tm[k]) * gg[k];
            imgdot[k] = fmaf(mix, wc, imgdot[k]);
        }
    }

    // ---- mixed disc target + squared error ----
    float rr[VEC] = {rd.x, rd.y, rd.z, rd.w};
    float gg[VEC] = {gd.x, gd.y, gd.z, gd.w};

    float sum = 0.f;
    #pragma unroll
    for (int k = 0; k < VEC; ++k) {
        const float target = tm[k] * rr[k] + (1.f - tm[k]) * gg[k];
        const float d = segdot[k] + imgdot[k] - target;
        sum = fmaf(d, d, sum);
    }

    // ---- wave (64) reduce, then block reduce, one partial per block ----
    #pragma unroll
    for (int off = 32; off > 0; off >>= 1)
        sum += __shfl_down(sum, off, 64);

    __shared__ float lsum[BLOCK / 64];
    const int wid  = threadIdx.x >> 6;
    const int lane = threadIdx.x & 63;
    if (lane == 0) lsum[wid] = sum;
    __syncthreads();
    if (threadIdx.x == 0) {
        float s = 0.f;
        #pragma unroll
        for (int i = 0; i < BLOCK / 64; ++i) s += lsum[i];
        partial[blockIdx.x] = s;   // no atomic, no init needed
    }
}

// Deterministic finalize: 1024 partials -> scalar mean.
__global__ __launch_bounds__(256) void finalize_kernel(
    const float* __restrict__ partial, float* __restrict__ out)
{
    const v4f* p4 = (const v4f*)partial;           // 1024 / 4 = 256
    v4f v = p4[threadIdx.x];
    float sum = v.x + v.y + v.z + v.w;

    #pragma unroll
    for (int off = 32; off > 0; off >>= 1)
        sum += __shfl_down(sum, off, 64);

    __shared__ float lsum[4];
    const int wid  = threadIdx.x >> 6;
    const int lane = threadIdx.x & 63;
    if (lane == 0) lsum[wid] = sum;
    __syncthreads();
    if (threadIdx.x == 0) {
        float s = lsum[0] + lsum[1] + lsum[2] + lsum[3];
        out[0] = s * (1.0f / (float)NPIX);
    }
}

extern "C" void kernel_launch(void* const* d_in, const int* in_sizes, int n_in,
                              void* d_out, int out_size, void* d_ws, size_t ws_size,
                              hipStream_t stream) {
    const float* real  = (const float*)d_in[0];
    const float* gen   = (const float*)d_in[1];
    const float* seg   = (const float*)d_in[2];
    const float* rdisc = (const float*)d_in[3];
    const float* gdisc = (const float*)d_in[4];
    const float* w     = (const float*)d_in[5];
    const int*   lut   = (const int*)d_in[6];
    float* out     = (float*)d_out;
    float* partial = (float*)d_ws;   // GRID floats of scratch

    labelmix_partial_kernel<<<GRID, BLOCK, 0, stream>>>(
        real, gen, seg, rdisc, gdisc, w, lut, partial);
    finalize_kernel<<<1, 256, 0, stream>>>(partial, out);
}